// Round 2
// baseline (174.738 us; speedup 1.0000x reference)
//
#include <hip/hip_runtime.h>
#include <hip/hip_bf16.h>

// Problem constants (fixed by setup_inputs)
#define B_ 8
#define N_ 16384
#define C_ 64
#define S_ 5

typedef float v4f __attribute__((ext_vector_type(4)));
typedef __bf16 v8bf __attribute__((ext_vector_type(8)));
typedef unsigned int v4u __attribute__((ext_vector_type(4)));

// fp32 -> bf16 bits, round-to-nearest-even (finite inputs only)
static __device__ __forceinline__ unsigned short f2bf(float f) {
    unsigned int u = __float_as_uint(f);
    u += 0x7fffu + ((u >> 16) & 1u);
    return (unsigned short)(u >> 16);
}
static __device__ __forceinline__ float bf2f(unsigned short s) {
    return __uint_as_float(((unsigned int)s) << 16);
}
// pack two f32 -> one dword of 2 bf16 (v_cvt_pk path)
static __device__ __forceinline__ unsigned int pk2bf(float a, float b) {
    float2 f2; f2.x = a; f2.y = b;
    __hip_bfloat162 h2 = __float22bfloat162_rn(f2);
    unsigned int u; __builtin_memcpy(&u, &h2, 4);
    return u;
}

// ---------------------------------------------------------------------------
// Kernel 1: prep_all — three independent block roles in ONE launch:
//   blocks 0..7   : FPS (batch = blk) + sampled-bg gather + ebb constants
//   block  8      : BN-folded weight prep (bf16 Wa', Wc', W2', bb1, bb2)
//   blocks 9..104 : fg_xyz passthrough copy (1 float4/thread)
// R6 FPS rework: ONE barrier per step (was 2, orig 3).
//   - winner coords carried through the wave shuffle reduce -> next step's
//     (lx,ly,lz) come from LDS broadcast, no global p[last] on the chain
//   - wave leaders write {best,idx,x,y,z} to PARITY-alternating LDS
//     (WAR-free without a second barrier); all threads then redundantly
//     scan the 16 wave winners (broadcast reads, deterministic)
//   - winner indices kept in per-thread regs (static select, no s_idx)
// Tie-break preserved: ascending k / ascending wave scan + strict > keeps
// the lowest index among equal maxima (jnp.argmax = first max).
// ---------------------------------------------------------------------------
__global__ __launch_bounds__(1024) void prep_all(
    const float* __restrict__ bg_xyz, const float* __restrict__ bg_feat,
    const float* __restrict__ w1, const float* __restrict__ g1, const float* __restrict__ b1,
    const float* __restrict__ m1, const float* __restrict__ v1,
    const float* __restrict__ w2, const float* __restrict__ g2, const float* __restrict__ b2,
    const float* __restrict__ m2, const float* __restrict__ v2,
    const float* __restrict__ fg_xyz, float* __restrict__ out_xyz,
    float* __restrict__ bb1, float* __restrict__ bb2,
    unsigned short* __restrict__ wa_bf, unsigned short* __restrict__ wc_bf,
    unsigned short* __restrict__ w2_bf,
    float* __restrict__ sbg, float* __restrict__ ebb) {
    const int blk = blockIdx.x;
    const int t = threadIdx.x;

    if (blk >= 9) { // ---- fg_xyz copy: 96 blocks x 1024 thr x 16B = 1.5 MB ----
        const int i = (blk - 9) * 1024 + t;
        ((float4*)out_xyz)[i] = ((const float4*)fg_xyz)[i];
        return;
    }

    if (blk == 8) { // ---- weight prep ----
        for (int i = t; i < 64 * 64; i += 1024) {
            const int o = i >> 6, c = i & 63;
            const float s1 = g1[o] / sqrtf(v1[o] + 1e-5f);
            const float s2 = g2[o] / sqrtf(v2[o] + 1e-5f);
            const float a = s1 * w1[o * 128 + c];
            const float bbv = s1 * w1[o * 128 + 64 + c];
            wa_bf[o * 64 + c] = f2bf(a);
            wc_bf[o * 64 + c] = f2bf(a + bbv);
            w2_bf[o * 64 + c] = f2bf(s2 * w2[o * 64 + c]);
        }
        if (t < 64) {
            const float s1 = g1[t] / sqrtf(v1[t] + 1e-5f);
            const float s2 = g2[t] / sqrtf(v2[t] + 1e-5f);
            bb1[t] = b1[t] - m1[t] * s1;
            bb2[t] = b2[t] - m2[t] * s2;
        }
        return;
    }

    // ---- FPS for batch b = blk: 1024 threads x 16 points ----
    const int b = blk;
    const float* p = bg_xyz + (size_t)b * N_ * 3;

    float px[16], py[16], pz[16], dist[16];
    {
        const float4* pv = (const float4*)p + t * 12; // pts t*16 .. t*16+15
#pragma unroll
        for (int g = 0; g < 4; ++g) { // 4 points per group, 3 float4 per group
            float4 a = pv[g * 3 + 0];
            float4 bq = pv[g * 3 + 1];
            float4 c = pv[g * 3 + 2];
            px[g * 4 + 0] = a.x;  py[g * 4 + 0] = a.y;  pz[g * 4 + 0] = a.z;
            px[g * 4 + 1] = a.w;  py[g * 4 + 1] = bq.x; pz[g * 4 + 1] = bq.y;
            px[g * 4 + 2] = bq.z; py[g * 4 + 2] = bq.w; pz[g * 4 + 2] = c.x;
            px[g * 4 + 3] = c.y;  py[g * 4 + 3] = c.z;  pz[g * 4 + 3] = c.w;
            dist[g * 4 + 0] = 1e10f; dist[g * 4 + 1] = 1e10f;
            dist[g * 4 + 2] = 1e10f; dist[g * 4 + 3] = 1e10f;
        }
    }

    __shared__ float s_best[2][16];
    __shared__ int s_bidx[2][16];
    __shared__ float s_cx[2][16], s_cy[2][16], s_cz[2][16];
    __shared__ float sf[S_][64];

    // step-0 seed coords: point 0 (broadcast L2 load, once)
    float lx = p[0], ly = p[1], lz = p[2];
    int i1 = 0, i2 = 0, i3 = 0, i4 = 0; // per-thread copies of winners

    for (int step = 1; step < S_; ++step) {
        const int par = step & 1;
        float best = -1.0f;
        int bidx = 0;
        float bx = 0.f, by = 0.f, bz = 0.f;
#pragma unroll
        for (int k = 0; k < 16; ++k) {
            float dx = px[k] - lx, dy = py[k] - ly, dz = pz[k] - lz;
            float d = dx * dx + dy * dy + dz * dz;
            float nd = fminf(dist[k], d);
            dist[k] = nd;
            // strict >: keeps the LOWEST index within this thread (k ascending)
            if (nd > best) {
                best = nd; bidx = t * 16 + k;
                bx = px[k]; by = py[k]; bz = pz[k];
            }
        }
        // wave(64) reduce, carrying winner coords; tie -> smaller index
#pragma unroll
        for (int off = 32; off > 0; off >>= 1) {
            float ob = __shfl_down(best, off, 64);
            int oi = __shfl_down(bidx, off, 64);
            float ox = __shfl_down(bx, off, 64);
            float oy = __shfl_down(by, off, 64);
            float oz = __shfl_down(bz, off, 64);
            if (ob > best || (ob == best && oi < bidx)) {
                best = ob; bidx = oi; bx = ox; by = oy; bz = oz;
            }
        }
        if ((t & 63) == 0) {
            const int w = t >> 6;
            s_best[par][w] = best; s_bidx[par][w] = bidx;
            s_cx[par][w] = bx; s_cy[par][w] = by; s_cz[par][w] = bz;
        }
        __syncthreads(); // the ONLY barrier this step: wave winners ready
        // all threads scan the 16 wave winners (broadcast LDS reads);
        // identical data -> identical deterministic result in every thread
        float bb = s_best[par][0];
        int bi = s_bidx[par][0];
        lx = s_cx[par][0]; ly = s_cy[par][0]; lz = s_cz[par][0];
#pragma unroll
        for (int w = 1; w < 16; ++w) {
            float ob = s_best[par][w];
            int oi = s_bidx[par][w];
            if (ob > bb || (ob == bb && oi < bi)) {
                bb = ob; bi = oi;
                lx = s_cx[par][w]; ly = s_cy[par][w]; lz = s_cz[par][w];
            }
        }
        if (step == 1) i1 = bi;
        else if (step == 2) i2 = bi;
        else if (step == 3) i3 = bi;
        else i4 = bi;
        // WAR safety: parity buffer written next at step+2, which is after
        // every thread passed step+1's barrier -> reads here are ordered.
    }

    // ---- sbg gather + ebb = s1.*(W1b @ sbg) + bb1, computed from raw w1 ----
    // indices are in per-thread regs -> no barrier needed before the gather
    if (t < S_ * 64) {
        const int j = t >> 6, c = t & 63;
        const int sj = (j == 0) ? 0 : (j == 1) ? i1 : (j == 2) ? i2
                     : (j == 3) ? i3 : i4;
        sf[j][c] = bg_feat[(size_t)b * C_ * N_ + (size_t)c * N_ + sj];
    }
    __syncthreads();
    if (t < S_ * 64) {
        const int j = t >> 6, o = t & 63;
        const float s1 = g1[o] * rsqrtf(v1[o] + 1e-5f);
        const float4* wr = (const float4*)&w1[o * 128 + 64];
        float acc = 0.f;
#pragma unroll
        for (int c4 = 0; c4 < 16; ++c4) {
            float4 wv = wr[c4];
            acc += wv.x * sf[j][c4 * 4 + 0] + wv.y * sf[j][c4 * 4 + 1] +
                   wv.z * sf[j][c4 * 4 + 2] + wv.w * sf[j][c4 * 4 + 3];
        }
        sbg[(b * S_ + j) * 64 + o] = sf[j][o];
        ebb[(b * S_ + j) * 64 + o] = s1 * acc + (b1[o] - m1[o] * s1);
    }
}

// ---------------------------------------------------------------------------
// Kernel 2: main fused MLP — R1 structure (fastest measured): 2048 blocks
// (1 tile each), o-partitioned waves (wave wv owns o rows [16wv,16wv+16),
// 6 weight A-frags = 24KB/block from L2), bf16 Ft, per-slice barriers,
// Ht double-buffered on slice parity (6 barriers), packed v_cvt_pk bf16.
// Memory-roofline structure: single read of F (32MB), single write (32MB),
// fully coalesced 256B/instr loads, 0 LDS bank conflicts measured.
// NOTE (R6 audit): float2-widened staging was considered and REJECTED —
// even-row 288B-stride LDS writes compute to 4-way bank conflicts vs the
// current measured-0-conflict layout.
// MFMA layouts (HW-verified): A[m=lane&15][k=(lane>>4)*8+j];
// C/D: col=lane&15, row=(lane>>4)*4+reg.
// ---------------------------------------------------------------------------
#define PITCH 72 // shorts per LDS row: 2-way (free) bank aliasing on b64/b128

__global__ __launch_bounds__(256) void fusion_main(
    const float* __restrict__ fg_feat,
    const unsigned short* __restrict__ wa_bf, const unsigned short* __restrict__ wc_bf,
    const unsigned short* __restrict__ w2_bf,
    const float* __restrict__ bb1g, const float* __restrict__ bb2g,
    const float* __restrict__ ebbg, const float* __restrict__ sbgg,
    float* __restrict__ out) {
    __shared__ __align__(16) unsigned short Ft[64 * PITCH];     // 9.2 KB
    __shared__ __align__(16) unsigned short Ht[2][64 * PITCH];  // 18.4 KB (dbuf)
    __shared__ __align__(16) float cEbb[S_ * 64];
    __shared__ __align__(16) float cSbg[S_ * 64];
    __shared__ __align__(16) float cBb1[64];
    __shared__ __align__(16) float cBb2[64];

    const int t = threadIdx.x;
    const int b = blockIdx.y;
    const int n0 = blockIdx.x * 64;
    const float* Fg = fg_feat + (size_t)b * C_ * N_ + n0;

    // ---- stage F tile transposed (bf16) into Ft[n][c] ----
    {
        const int n = t & 63;
        const int cg = (t >> 6) * 16;
        float fr[16];
#pragma unroll
        for (int i = 0; i < 16; ++i) fr[i] = Fg[(size_t)(cg + i) * N_ + n];
        v4u w0, w1v;
#pragma unroll
        for (int i = 0; i < 8; ++i) {
            unsigned int pk = pk2bf(fr[2 * i], fr[2 * i + 1]);
            if (i < 4) w0[i] = pk; else w1v[i - 4] = pk;
        }
        *(v4u*)&Ft[n * PITCH + cg] = w0;
        *(v4u*)&Ft[n * PITCH + cg + 8] = w1v;
    }
    // ---- stage per-(b,slice) constants into LDS ----
    for (int i = t; i < S_ * 64; i += 256) {
        cEbb[i] = ebbg[b * (S_ * 64) + i];
        cSbg[i] = sbgg[b * (S_ * 64) + i];
    }
    if (t < 64) { cBb1[t] = bb1g[t]; cBb2[t] = bb2g[t]; }

    const int lane = t & 63;
    const int wv = t >> 6;     // wave id -> o-block (wave owns o rows [16wv,+16))
    const int o0 = wv * 16;
    const int m = lane & 15;   // A row / B col / D col
    const int q = lane >> 4;   // k-chunk / D row-group
    const int o4 = o0 + 4 * q; // this lane's 4-channel output group

    // weight A-frags: 6 per wave (24 KB/block total, L2-resident)
    const int arow = o0 + m;
    v8bf aWa[2], aWc[2], aW2[2];
#pragma unroll
    for (int ks = 0; ks < 2; ++ks) {
        aWa[ks] = *(const v8bf*)&wa_bf[arow * 64 + ks * 32 + q * 8];
        aWc[ks] = *(const v8bf*)&wc_bf[arow * 64 + ks * 32 + q * 8];
        aW2[ks] = *(const v8bf*)&w2_bf[arow * 64 + ks * 32 + q * 8];
    }

    __syncthreads(); // Ft + constants ready

    // B-frags of F: this wave needs all 64 columns (4 nb blocks)
    v8bf bF[4][2];
#pragma unroll
    for (int nb = 0; nb < 4; ++nb)
#pragma unroll
        for (int ks = 0; ks < 2; ++ks)
            bF[nb][ks] = *(const v8bf*)&Ft[(nb * 16 + m) * PITCH + ks * 32 + q * 8];

    // GEMM1: U = Wa'.F (slices>=1), U0 = Wc'.F (slice 0)
    v4f U[4], U0[4];
#pragma unroll
    for (int nb = 0; nb < 4; ++nb) {
        v4f z = {0.f, 0.f, 0.f, 0.f};
        z = __builtin_amdgcn_mfma_f32_16x16x32_bf16(aWa[0], bF[nb][0], z, 0, 0, 0);
        U[nb] = __builtin_amdgcn_mfma_f32_16x16x32_bf16(aWa[1], bF[nb][1], z, 0, 0, 0);
        v4f z2 = {0.f, 0.f, 0.f, 0.f};
        z2 = __builtin_amdgcn_mfma_f32_16x16x32_bf16(aWc[0], bF[nb][0], z2, 0, 0, 0);
        U0[nb] = __builtin_amdgcn_mfma_f32_16x16x32_bf16(aWc[1], bF[nb][1], z2, 0, 0, 0);
    }

    v4f acc[4];
#pragma unroll
    for (int nb = 0; nb < 4; ++nb) acc[nb] = (v4f){0.f, 0.f, 0.f, 0.f};

    const v4f bb2r = *(const v4f*)&cBb2[o4];

#pragma unroll
    for (int s = 0; s < 6; ++s) {
        unsigned short* h = &Ht[s & 1][0]; // slice-parity double buffer
        // layer-1 constant for this lane's 4 channels (from LDS, per slice)
        v4f cv = (s == 0) ? *(const v4f*)&cBb1[o4]
                          : *(const v4f*)&cEbb[(s - 1) * 64 + o4];
        // form H (C-layout, rows o4..o4+3) -> Ht[n][o] transposed
#pragma unroll
        for (int nb = 0; nb < 4; ++nb) {
            v4f u = (s == 0) ? U0[nb] : U[nb];
            unsigned int lo = pk2bf(fmaxf(u[0] + cv[0], 0.f), fmaxf(u[1] + cv[1], 0.f));
            unsigned int hi = pk2bf(fmaxf(u[2] + cv[2], 0.f), fmaxf(u[3] + cv[3], 0.f));
            unsigned long long vv = (unsigned long long)lo | ((unsigned long long)hi << 32);
            *(unsigned long long*)&h[(nb * 16 + m) * PITCH + o4] = vv;
        }
        __syncthreads(); // Ht[s&1] ready (WAR vs slice s+2 is covered by the
                         // pre-barrier lgkmcnt(0) drain of slice s's reads)

        // GEMM2 p = W2'.H + epilogue: acc += relu(p + bb2) * multiplier
#pragma unroll
        for (int nb = 0; nb < 4; ++nb) {
            v8bf h0 = *(const v8bf*)&h[(nb * 16 + m) * PITCH + q * 8];
            v8bf h1 = *(const v8bf*)&h[(nb * 16 + m) * PITCH + 32 + q * 8];
            v4f z = {0.f, 0.f, 0.f, 0.f};
            z = __builtin_amdgcn_mfma_f32_16x16x32_bf16(aW2[0], h0, z, 0, 0, 0);
            v4f p4 = __builtin_amdgcn_mfma_f32_16x16x32_bf16(aW2[1], h1, z, 0, 0, 0);

            if (s == 0) {
                unsigned long long fv =
                    *(const unsigned long long*)&Ft[(nb * 16 + m) * PITCH + o4];
#pragma unroll
                for (int r = 0; r < 4; ++r) {
                    float wgt = fmaxf(p4[r] + bb2r[r], 0.f);
                    acc[nb][r] += wgt * bf2f((unsigned short)(fv >> (16 * r)));
                }
            } else {
                const v4f sb = *(const v4f*)&cSbg[(s - 1) * 64 + o4];
#pragma unroll
                for (int r = 0; r < 4; ++r) {
                    float wgt = fmaxf(p4[r] + bb2r[r], 0.f);
                    acc[nb][r] += wgt * sb[r];
                }
            }
        }
    }

    // store: out[b][o][n], o = o4+r, n = n0 + nb*16 + m
    const size_t outb = (size_t)b * C_ * N_ + n0;
#pragma unroll
    for (int nb = 0; nb < 4; ++nb)
#pragma unroll
        for (int r = 0; r < 4; ++r)
            out[outb + (size_t)(o4 + r) * N_ + (nb * 16 + m)] = acc[nb][r];
}

// ---------------------------------------------------------------------------
extern "C" void kernel_launch(void* const* d_in, const int* in_sizes, int n_in,
                              void* d_out, int out_size, void* d_ws, size_t ws_size,
                              hipStream_t stream) {
    const float* fg_xyz = (const float*)d_in[0];
    const float* fg_feat = (const float*)d_in[1];
    const float* bg_xyz = (const float*)d_in[2];
    const float* bg_feat = (const float*)d_in[3];
    const float* w1 = (const float*)d_in[4];
    const float* g1 = (const float*)d_in[5];
    const float* b1 = (const float*)d_in[6];
    const float* m1 = (const float*)d_in[7];
    const float* v1 = (const float*)d_in[8];
    const float* w2 = (const float*)d_in[9];
    const float* g2 = (const float*)d_in[10];
    const float* b2 = (const float*)d_in[11];
    const float* m2 = (const float*)d_in[12];
    const float* v2 = (const float*)d_in[13];

    // workspace layout (float units)
    float* ws = (float*)d_ws;
    float* ebb = ws;                        // 2560
    float* sbg = ebb + 2560;                // 2560
    float* bb1 = sbg + 2560;                // 64
    float* bb2 = bb1 + 64;                  // 64
    unsigned short* wa_bf = (unsigned short*)(bb2 + 64); // 4096 shorts
    unsigned short* wc_bf = wa_bf + 4096;
    unsigned short* w2_bf = wc_bf + 4096;

    float* out_feats = (float*)d_out + (size_t)B_ * N_ * 3;

    // node 1: FPS+sbg+ebb (blocks 0..7) | weight prep (8) | xyz copy (9..104)
    prep_all<<<105, 1024, 0, stream>>>(bg_xyz, bg_feat,
                                       w1, g1, b1, m1, v1, w2, g2, b2, m2, v2,
                                       fg_xyz, (float*)d_out,
                                       bb1, bb2, wa_bf, wc_bf, w2_bf, sbg, ebb);
    // node 2: fused MLP — 2048 blocks, 1 tile each (R1 grid)
    fusion_main<<<dim3(N_ / 64, B_), 256, 0, stream>>>(
        fg_feat, wa_bf, wc_bf, w2_bf, bb1, bb2, ebb, sbg, out_feats);
}

// Round 3
// 159.113 us; speedup vs baseline: 1.0982x; 1.0982x over previous
//
#include <hip/hip_runtime.h>
#include <hip/hip_bf16.h>

// Problem constants (fixed by setup_inputs)
#define B_ 8
#define N_ 16384
#define C_ 64
#define S_ 5

typedef float v4f __attribute__((ext_vector_type(4)));
typedef __bf16 v8bf __attribute__((ext_vector_type(8)));
typedef unsigned int v4u __attribute__((ext_vector_type(4)));

// fp32 -> bf16 bits, round-to-nearest-even (finite inputs only)
static __device__ __forceinline__ unsigned short f2bf(float f) {
    unsigned int u = __float_as_uint(f);
    u += 0x7fffu + ((u >> 16) & 1u);
    return (unsigned short)(u >> 16);
}
static __device__ __forceinline__ float bf2f(unsigned short s) {
    return __uint_as_float(((unsigned int)s) << 16);
}
// pack two f32 -> one dword of 2 bf16 (v_cvt_pk path)
static __device__ __forceinline__ unsigned int pk2bf(float a, float b) {
    float2 f2; f2.x = a; f2.y = b;
    __hip_bfloat162 h2 = __float22bfloat162_rn(f2);
    unsigned int u; __builtin_memcpy(&u, &h2, 4);
    return u;
}

// ---------------------------------------------------------------------------
// Kernel 1: prep_all — three independent block roles in ONE launch:
//   blocks 0..7   : FPS (batch = blk) + sampled-bg gather + ebb constants
//   block  8      : BN-folded weight prep (bf16 Wa', Wc', W2', bb1, bb2)
//   blocks 9..104 : fg_xyz passthrough copy (1 float4/thread)
// R7: EXACT REVERT to the R1-measured version (160.2 us) — R2's 1-barrier
// variant coincided with a +14.5 us regression that counter evidence could
// not attribute (fills unchanged, host env degraded). Re-establishing the
// best-known baseline for clean A/B.
// FPS step sync: 2 barriers; wave(64) shfl reduce then wave-0 16-lane
// shfl reduce. Tie-break: strict > + ascending order = jnp.argmax first-max.
// ---------------------------------------------------------------------------
__global__ __launch_bounds__(1024) void prep_all(
    const float* __restrict__ bg_xyz, const float* __restrict__ bg_feat,
    const float* __restrict__ w1, const float* __restrict__ g1, const float* __restrict__ b1,
    const float* __restrict__ m1, const float* __restrict__ v1,
    const float* __restrict__ w2, const float* __restrict__ g2, const float* __restrict__ b2,
    const float* __restrict__ m2, const float* __restrict__ v2,
    const float* __restrict__ fg_xyz, float* __restrict__ out_xyz,
    float* __restrict__ bb1, float* __restrict__ bb2,
    unsigned short* __restrict__ wa_bf, unsigned short* __restrict__ wc_bf,
    unsigned short* __restrict__ w2_bf,
    float* __restrict__ sbg, float* __restrict__ ebb) {
    const int blk = blockIdx.x;
    const int t = threadIdx.x;

    if (blk >= 9) { // ---- fg_xyz copy: 96 blocks x 1024 thr x 16B = 1.5 MB ----
        const int i = (blk - 9) * 1024 + t;
        ((float4*)out_xyz)[i] = ((const float4*)fg_xyz)[i];
        return;
    }

    if (blk == 8) { // ---- weight prep ----
        for (int i = t; i < 64 * 64; i += 1024) {
            const int o = i >> 6, c = i & 63;
            const float s1 = g1[o] / sqrtf(v1[o] + 1e-5f);
            const float s2 = g2[o] / sqrtf(v2[o] + 1e-5f);
            const float a = s1 * w1[o * 128 + c];
            const float bbv = s1 * w1[o * 128 + 64 + c];
            wa_bf[o * 64 + c] = f2bf(a);
            wc_bf[o * 64 + c] = f2bf(a + bbv);
            w2_bf[o * 64 + c] = f2bf(s2 * w2[o * 64 + c]);
        }
        if (t < 64) {
            const float s1 = g1[t] / sqrtf(v1[t] + 1e-5f);
            const float s2 = g2[t] / sqrtf(v2[t] + 1e-5f);
            bb1[t] = b1[t] - m1[t] * s1;
            bb2[t] = b2[t] - m2[t] * s2;
        }
        return;
    }

    // ---- FPS for batch b = blk: 1024 threads x 16 points ----
    const int b = blk;
    const float* p = bg_xyz + (size_t)b * N_ * 3;

    float px[16], py[16], pz[16], dist[16];
    {
        const float4* pv = (const float4*)p + t * 12; // pts t*16 .. t*16+15
#pragma unroll
        for (int g = 0; g < 4; ++g) { // 4 points per group, 3 float4 per group
            float4 a = pv[g * 3 + 0];
            float4 bq = pv[g * 3 + 1];
            float4 c = pv[g * 3 + 2];
            px[g * 4 + 0] = a.x;  py[g * 4 + 0] = a.y;  pz[g * 4 + 0] = a.z;
            px[g * 4 + 1] = a.w;  py[g * 4 + 1] = bq.x; pz[g * 4 + 1] = bq.y;
            px[g * 4 + 2] = bq.z; py[g * 4 + 2] = bq.w; pz[g * 4 + 2] = c.x;
            px[g * 4 + 3] = c.y;  py[g * 4 + 3] = c.z;  pz[g * 4 + 3] = c.w;
            dist[g * 4 + 0] = 1e10f; dist[g * 4 + 1] = 1e10f;
            dist[g * 4 + 2] = 1e10f; dist[g * 4 + 3] = 1e10f;
        }
    }

    __shared__ float s_best[16];
    __shared__ int s_bidx[16];
    __shared__ int s_last;
    __shared__ int s_idx[S_];
    __shared__ float sf[S_][64];
    int last = 0;
    if (t == 0) s_idx[0] = 0;

    for (int step = 1; step < S_; ++step) {
        const float lx = p[last * 3 + 0];
        const float ly = p[last * 3 + 1];
        const float lz = p[last * 3 + 2];
        float best = -1.0f;
        int bidx = 0;
#pragma unroll
        for (int k = 0; k < 16; ++k) {
            float dx = px[k] - lx, dy = py[k] - ly, dz = pz[k] - lz;
            float d = dx * dx + dy * dy + dz * dz;
            float nd = fminf(dist[k], d);
            dist[k] = nd;
            // strict >: keeps the LOWEST index within this thread (k ascending)
            if (nd > best) { best = nd; bidx = t * 16 + k; }
        }
        // wave(64) reduce; tie -> smaller index (jnp.argmax = first max)
#pragma unroll
        for (int off = 32; off > 0; off >>= 1) {
            float ob = __shfl_down(best, off, 64);
            int oi = __shfl_down(bidx, off, 64);
            if (ob > best || (ob == best && oi < bidx)) { best = ob; bidx = oi; }
        }
        if ((t & 63) == 0) { s_best[t >> 6] = best; s_bidx[t >> 6] = bidx; }
        __syncthreads(); // bar1: s_best/s_bidx ready
        if (t < 16) {    // wave-0 16-lane shfl reduce (replaces serial scan)
            float bb = s_best[t];
            int bi = s_bidx[t];
#pragma unroll
            for (int off = 8; off > 0; off >>= 1) {
                float ob = __shfl_down(bb, off, 16);
                int oi = __shfl_down(bi, off, 16);
                if (ob > bb || (ob == bb && oi < bi)) { bb = ob; bi = oi; }
            }
            if (t == 0) { s_last = bi; s_idx[step] = bi; }
        }
        __syncthreads(); // bar2: s_last ready; also orders next s_best writes
        last = s_last;
    }

    // ---- sbg gather + ebb = s1.*(W1b @ sbg) + bb1, computed from raw w1 ----
    __syncthreads();
    if (t < S_ * 64) {
        const int j = t >> 6, c = t & 63;
        sf[j][c] = bg_feat[(size_t)b * C_ * N_ + (size_t)c * N_ + s_idx[j]];
    }
    __syncthreads();
    if (t < S_ * 64) {
        const int j = t >> 6, o = t & 63;
        const float s1 = g1[o] * rsqrtf(v1[o] + 1e-5f);
        const float4* wr = (const float4*)&w1[o * 128 + 64];
        float acc = 0.f;
#pragma unroll
        for (int c4 = 0; c4 < 16; ++c4) {
            float4 wv = wr[c4];
            acc += wv.x * sf[j][c4 * 4 + 0] + wv.y * sf[j][c4 * 4 + 1] +
                   wv.z * sf[j][c4 * 4 + 2] + wv.w * sf[j][c4 * 4 + 3];
        }
        sbg[(b * S_ + j) * 64 + o] = sf[j][o];
        ebb[(b * S_ + j) * 64 + o] = s1 * acc + (b1[o] - m1[o] * s1);
    }
}

// ---------------------------------------------------------------------------
// Kernel 2: main fused MLP — R1 structure (fastest measured): 2048 blocks
// (1 tile each), o-partitioned waves (wave wv owns o rows [16wv,16wv+16),
// 6 weight A-frags = 24KB/block from L2), bf16 Ft, per-slice barriers,
// Ht double-buffered on slice parity (6 barriers), packed v_cvt_pk bf16.
// Memory-roofline structure: single read of F (32MB), single write (32MB),
// fully coalesced 256B/instr loads, 0 LDS bank conflicts measured.
// MFMA layouts (HW-verified): A[m=lane&15][k=(lane>>4)*8+j];
// C/D: col=lane&15, row=(lane>>4)*4+reg.
// ---------------------------------------------------------------------------
#define PITCH 72 // shorts per LDS row: 2-way (free) bank aliasing on b64/b128

__global__ __launch_bounds__(256) void fusion_main(
    const float* __restrict__ fg_feat,
    const unsigned short* __restrict__ wa_bf, const unsigned short* __restrict__ wc_bf,
    const unsigned short* __restrict__ w2_bf,
    const float* __restrict__ bb1g, const float* __restrict__ bb2g,
    const float* __restrict__ ebbg, const float* __restrict__ sbgg,
    float* __restrict__ out) {
    __shared__ __align__(16) unsigned short Ft[64 * PITCH];     // 9.2 KB
    __shared__ __align__(16) unsigned short Ht[2][64 * PITCH];  // 18.4 KB (dbuf)
    __shared__ __align__(16) float cEbb[S_ * 64];
    __shared__ __align__(16) float cSbg[S_ * 64];
    __shared__ __align__(16) float cBb1[64];
    __shared__ __align__(16) float cBb2[64];

    const int t = threadIdx.x;
    const int b = blockIdx.y;
    const int n0 = blockIdx.x * 64;
    const float* Fg = fg_feat + (size_t)b * C_ * N_ + n0;

    // ---- stage F tile transposed (bf16) into Ft[n][c] ----
    {
        const int n = t & 63;
        const int cg = (t >> 6) * 16;
        float fr[16];
#pragma unroll
        for (int i = 0; i < 16; ++i) fr[i] = Fg[(size_t)(cg + i) * N_ + n];
        v4u w0, w1v;
#pragma unroll
        for (int i = 0; i < 8; ++i) {
            unsigned int pk = pk2bf(fr[2 * i], fr[2 * i + 1]);
            if (i < 4) w0[i] = pk; else w1v[i - 4] = pk;
        }
        *(v4u*)&Ft[n * PITCH + cg] = w0;
        *(v4u*)&Ft[n * PITCH + cg + 8] = w1v;
    }
    // ---- stage per-(b,slice) constants into LDS ----
    for (int i = t; i < S_ * 64; i += 256) {
        cEbb[i] = ebbg[b * (S_ * 64) + i];
        cSbg[i] = sbgg[b * (S_ * 64) + i];
    }
    if (t < 64) { cBb1[t] = bb1g[t]; cBb2[t] = bb2g[t]; }

    const int lane = t & 63;
    const int wv = t >> 6;     // wave id -> o-block (wave owns o rows [16wv,+16))
    const int o0 = wv * 16;
    const int m = lane & 15;   // A row / B col / D col
    const int q = lane >> 4;   // k-chunk / D row-group
    const int o4 = o0 + 4 * q; // this lane's 4-channel output group

    // weight A-frags: 6 per wave (24 KB/block total, L2-resident)
    const int arow = o0 + m;
    v8bf aWa[2], aWc[2], aW2[2];
#pragma unroll
    for (int ks = 0; ks < 2; ++ks) {
        aWa[ks] = *(const v8bf*)&wa_bf[arow * 64 + ks * 32 + q * 8];
        aWc[ks] = *(const v8bf*)&wc_bf[arow * 64 + ks * 32 + q * 8];
        aW2[ks] = *(const v8bf*)&w2_bf[arow * 64 + ks * 32 + q * 8];
    }

    __syncthreads(); // Ft + constants ready

    // B-frags of F: this wave needs all 64 columns (4 nb blocks)
    v8bf bF[4][2];
#pragma unroll
    for (int nb = 0; nb < 4; ++nb)
#pragma unroll
        for (int ks = 0; ks < 2; ++ks)
            bF[nb][ks] = *(const v8bf*)&Ft[(nb * 16 + m) * PITCH + ks * 32 + q * 8];

    // GEMM1: U = Wa'.F (slices>=1), U0 = Wc'.F (slice 0)
    v4f U[4], U0[4];
#pragma unroll
    for (int nb = 0; nb < 4; ++nb) {
        v4f z = {0.f, 0.f, 0.f, 0.f};
        z = __builtin_amdgcn_mfma_f32_16x16x32_bf16(aWa[0], bF[nb][0], z, 0, 0, 0);
        U[nb] = __builtin_amdgcn_mfma_f32_16x16x32_bf16(aWa[1], bF[nb][1], z, 0, 0, 0);
        v4f z2 = {0.f, 0.f, 0.f, 0.f};
        z2 = __builtin_amdgcn_mfma_f32_16x16x32_bf16(aWc[0], bF[nb][0], z2, 0, 0, 0);
        U0[nb] = __builtin_amdgcn_mfma_f32_16x16x32_bf16(aWc[1], bF[nb][1], z2, 0, 0, 0);
    }

    v4f acc[4];
#pragma unroll
    for (int nb = 0; nb < 4; ++nb) acc[nb] = (v4f){0.f, 0.f, 0.f, 0.f};

    const v4f bb2r = *(const v4f*)&cBb2[o4];

#pragma unroll
    for (int s = 0; s < 6; ++s) {
        unsigned short* h = &Ht[s & 1][0]; // slice-parity double buffer
        // layer-1 constant for this lane's 4 channels (from LDS, per slice)
        v4f cv = (s == 0) ? *(const v4f*)&cBb1[o4]
                          : *(const v4f*)&cEbb[(s - 1) * 64 + o4];
        // form H (C-layout, rows o4..o4+3) -> Ht[n][o] transposed
#pragma unroll
        for (int nb = 0; nb < 4; ++nb) {
            v4f u = (s == 0) ? U0[nb] : U[nb];
            unsigned int lo = pk2bf(fmaxf(u[0] + cv[0], 0.f), fmaxf(u[1] + cv[1], 0.f));
            unsigned int hi = pk2bf(fmaxf(u[2] + cv[2], 0.f), fmaxf(u[3] + cv[3], 0.f));
            unsigned long long vv = (unsigned long long)lo | ((unsigned long long)hi << 32);
            *(unsigned long long*)&h[(nb * 16 + m) * PITCH + o4] = vv;
        }
        __syncthreads(); // Ht[s&1] ready (WAR vs slice s+2 is covered by the
                         // pre-barrier lgkmcnt(0) drain of slice s's reads)

        // GEMM2 p = W2'.H + epilogue: acc += relu(p + bb2) * multiplier
#pragma unroll
        for (int nb = 0; nb < 4; ++nb) {
            v8bf h0 = *(const v8bf*)&h[(nb * 16 + m) * PITCH + q * 8];
            v8bf h1 = *(const v8bf*)&h[(nb * 16 + m) * PITCH + 32 + q * 8];
            v4f z = {0.f, 0.f, 0.f, 0.f};
            z = __builtin_amdgcn_mfma_f32_16x16x32_bf16(aW2[0], h0, z, 0, 0, 0);
            v4f p4 = __builtin_amdgcn_mfma_f32_16x16x32_bf16(aW2[1], h1, z, 0, 0, 0);

            if (s == 0) {
                unsigned long long fv =
                    *(const unsigned long long*)&Ft[(nb * 16 + m) * PITCH + o4];
#pragma unroll
                for (int r = 0; r < 4; ++r) {
                    float wgt = fmaxf(p4[r] + bb2r[r], 0.f);
                    acc[nb][r] += wgt * bf2f((unsigned short)(fv >> (16 * r)));
                }
            } else {
                const v4f sb = *(const v4f*)&cSbg[(s - 1) * 64 + o4];
#pragma unroll
                for (int r = 0; r < 4; ++r) {
                    float wgt = fmaxf(p4[r] + bb2r[r], 0.f);
                    acc[nb][r] += wgt * sb[r];
                }
            }
        }
    }

    // store: out[b][o][n], o = o4+r, n = n0 + nb*16 + m
    const size_t outb = (size_t)b * C_ * N_ + n0;
#pragma unroll
    for (int nb = 0; nb < 4; ++nb)
#pragma unroll
        for (int r = 0; r < 4; ++r)
            out[outb + (size_t)(o4 + r) * N_ + (nb * 16 + m)] = acc[nb][r];
}

// ---------------------------------------------------------------------------
extern "C" void kernel_launch(void* const* d_in, const int* in_sizes, int n_in,
                              void* d_out, int out_size, void* d_ws, size_t ws_size,
                              hipStream_t stream) {
    const float* fg_xyz = (const float*)d_in[0];
    const float* fg_feat = (const float*)d_in[1];
    const float* bg_xyz = (const float*)d_in[2];
    const float* bg_feat = (const float*)d_in[3];
    const float* w1 = (const float*)d_in[4];
    const float* g1 = (const float*)d_in[5];
    const float* b1 = (const float*)d_in[6];
    const float* m1 = (const float*)d_in[7];
    const float* v1 = (const float*)d_in[8];
    const float* w2 = (const float*)d_in[9];
    const float* g2 = (const float*)d_in[10];
    const float* b2 = (const float*)d_in[11];
    const float* m2 = (const float*)d_in[12];
    const float* v2 = (const float*)d_in[13];

    // workspace layout (float units)
    float* ws = (float*)d_ws;
    float* ebb = ws;                        // 2560
    float* sbg = ebb + 2560;                // 2560
    float* bb1 = sbg + 2560;                // 64
    float* bb2 = bb1 + 64;                  // 64
    unsigned short* wa_bf = (unsigned short*)(bb2 + 64); // 4096 shorts
    unsigned short* wc_bf = wa_bf + 4096;
    unsigned short* w2_bf = wc_bf + 4096;

    float* out_feats = (float*)d_out + (size_t)B_ * N_ * 3;

    // node 1: FPS+sbg+ebb (blocks 0..7) | weight prep (8) | xyz copy (9..104)
    prep_all<<<105, 1024, 0, stream>>>(bg_xyz, bg_feat,
                                       w1, g1, b1, m1, v1, w2, g2, b2, m2, v2,
                                       fg_xyz, (float*)d_out,
                                       bb1, bb2, wa_bf, wc_bf, w2_bf, sbg, ebb);
    // node 2: fused MLP — 2048 blocks, 1 tile each (R1 grid)
    fusion_main<<<dim3(N_ / 64, B_), 256, 0, stream>>>(
        fg_feat, wa_bf, wc_bf, w2_bf, bb1, bb2, ebb, sbg, out_feats);
}